// Round 2
// baseline (135.435 us; speedup 1.0000x reference)
//
#include <hip/hip_runtime.h>
#include <hip/hip_cooperative_groups.h>
#include <math.h>

namespace cg = cooperative_groups;

// Geometry (fixed by the reference).
#define HS   2048          // hidden size (output columns)
#define DIN  2048          // input dim (reduction rows)
#define NBLK 512           // grid size (2 blocks/CU on 256 CUs)
#define ROWS 16            // rows per split (DIN / (NBLK/4))

// Single fused cooperative kernel.
//   Phase A: zero the 2x2048 fp32 accumulators (blocks 0..15)
//   Phase B: paired GEMV  z_g = x @ w_xg + h0 @ w_hg  for g in {f, o},
//            split-K over 128 row-slices, device-scope atomicAdd
//   Phase C: block 0: gates + dot-cancelled normalization + output
// Algebra: cell = f*c0 + dot(i,c) (scalar broadcast); mean/std-normalization
// cancels the constant shift, so h = o * tanh(norm(f*c0)). i/c gates dead.
__global__ __launch_bounds__(256) void lstm_fused(
        const float* __restrict__ x,    const float* __restrict__ h0,
        const float* __restrict__ w_xf, const float* __restrict__ w_hf,
        const float* __restrict__ w_xo, const float* __restrict__ w_ho,
        const float* __restrict__ b_f,  const float* __restrict__ b_o,
        const float* __restrict__ c0,   float* __restrict__ out,
        float* __restrict__ acc /* [0..2047]=f, [2048..4095]=o */) {
    cg::grid_group grid = cg::this_grid();
    const int bid = blockIdx.x;
    const int tid = threadIdx.x;

    // ---- Phase A: zero accumulators (must re-init every call: the harness
    // poisons d_ws once and never re-poisons between replays) ----
    if (bid < 16) acc[bid * 256 + tid] = 0.0f;
    __threadfence();
    grid.sync();

    // ---- Phase B: paired partial GEMV ----
    // bid = split*4 + g*2 + cc ; split in [0,128), g in {f,o}, cc = col half
    const int split = bid >> 2;
    const int g     = (bid >> 1) & 1;
    const int cc    = bid & 1;
    const float* W1 = g ? w_xo : w_xf;   // multiplied by x
    const float* W2 = g ? w_ho : w_hf;   // multiplied by h0
    float* ac       = acc + g * HS;

    const int j0 = cc * 1024 + tid * 4;  // this thread's float4 column
    const int d0 = split * ROWS;         // first row of this block's slice
    const float* p1 = W1 + (size_t)d0 * HS + j0;
    const float* p2 = W2 + (size_t)d0 * HS + j0;

    float4 a = make_float4(0.f, 0.f, 0.f, 0.f);
#pragma unroll
    for (int r = 0; r < ROWS; ++r) {
        const float  v1 = x[d0 + r];     // block-uniform -> scalar load
        const float  v2 = h0[d0 + r];
        const float4 w1 = *reinterpret_cast<const float4*>(p1 + (size_t)r * HS);
        const float4 w2 = *reinterpret_cast<const float4*>(p2 + (size_t)r * HS);
        a.x = fmaf(v1, w1.x, fmaf(v2, w2.x, a.x));
        a.y = fmaf(v1, w1.y, fmaf(v2, w2.y, a.y));
        a.z = fmaf(v1, w1.z, fmaf(v2, w2.z, a.z));
        a.w = fmaf(v1, w1.w, fmaf(v2, w2.w, a.w));
    }
    atomicAdd(&ac[j0 + 0], a.x);
    atomicAdd(&ac[j0 + 1], a.y);
    atomicAdd(&ac[j0 + 2], a.z);
    atomicAdd(&ac[j0 + 3], a.w);

    grid.sync();

    // ---- Phase C: finalize on block 0 ----
    if (bid != 0) return;

    const int lane = tid & 63;
    const int wv   = tid >> 6;
    __shared__ float red[2][4];

    float v[8], og[8];
    float lsum = 0.f;
#pragma unroll
    for (int k = 0; k < 2; ++k) {
        const int j = tid * 8 + k * 4;
        const float4 zf = *reinterpret_cast<const float4*>(acc + j);
        const float4 zo = *reinterpret_cast<const float4*>(acc + HS + j);
        const float4 bf = *reinterpret_cast<const float4*>(b_f + j);
        const float4 bo = *reinterpret_cast<const float4*>(b_o + j);
        const float4 cv = *reinterpret_cast<const float4*>(c0 + j);
        const float zfv[4] = {zf.x + bf.x, zf.y + bf.y, zf.z + bf.z, zf.w + bf.w};
        const float zov[4] = {zo.x + bo.x, zo.y + bo.y, zo.z + bo.z, zo.w + bo.w};
        const float ccv[4] = {cv.x, cv.y, cv.z, cv.w};
#pragma unroll
        for (int q = 0; q < 4; ++q) {
            const float fg = 1.f / (1.f + expf(-zfv[q]));
            const float oo = 1.f / (1.f + expf(-zov[q]));
            const float vv = fg * ccv[q];
            v[k * 4 + q]  = vv;
            og[k * 4 + q] = oo;
            lsum += vv;
        }
    }

    // block-reduce sum(v) -> mean
#pragma unroll
    for (int s = 32; s > 0; s >>= 1) lsum += __shfl_down(lsum, s);
    if (lane == 0) red[0][wv] = lsum;
    __syncthreads();
    const float mean = (red[0][0] + red[0][1] + red[0][2] + red[0][3]) * (1.f / 2048.f);

    // block-reduce sum((v-mean)^2) -> std (ddof=1)
    float lss = 0.f;
#pragma unroll
    for (int e = 0; e < 8; ++e) {
        const float d = v[e] - mean;
        lss += d * d;
    }
#pragma unroll
    for (int s = 32; s > 0; s >>= 1) lss += __shfl_down(lss, s);
    if (lane == 0) red[1][wv] = lss;
    __syncthreads();
    const float var = (red[1][0] + red[1][1] + red[1][2] + red[1][3]) * (1.f / 2047.f);
    const float inv = 1.f / (sqrtf(var) + 1e-5f);

#pragma unroll
    for (int k = 0; k < 2; ++k) {
        const int j = tid * 8 + k * 4;
        float4 r;
        r.x = og[k * 4 + 0] * tanhf((v[k * 4 + 0] - mean) * inv);
        r.y = og[k * 4 + 1] * tanhf((v[k * 4 + 1] - mean) * inv);
        r.z = og[k * 4 + 2] * tanhf((v[k * 4 + 2] - mean) * inv);
        r.w = og[k * 4 + 3] * tanhf((v[k * 4 + 3] - mean) * inv);
        *reinterpret_cast<float4*>(out + j) = r;
    }
}

extern "C" void kernel_launch(void* const* d_in, const int* in_sizes, int n_in,
                              void* d_out, int out_size, void* d_ws, size_t ws_size,
                              hipStream_t stream) {
    // setup_inputs order:
    // 0:x 1:w_xi 2:w_xf 3:w_xo 4:w_xc 5:w_hi 6:w_hf 7:w_ho 8:w_hc
    // 9:b_i 10:b_f 11:b_o 12:b_c 13:h0 14:c0
    const float* x    = (const float*)d_in[0];
    const float* w_xf = (const float*)d_in[2];
    const float* w_xo = (const float*)d_in[3];
    const float* w_hf = (const float*)d_in[6];
    const float* w_ho = (const float*)d_in[7];
    const float* b_f  = (const float*)d_in[10];
    const float* b_o  = (const float*)d_in[11];
    const float* h0   = (const float*)d_in[13];
    const float* c0   = (const float*)d_in[14];
    float* out = (float*)d_out;
    float* acc = (float*)d_ws;  // 4096 fp32

    void* args[] = {&x, &h0, &w_xf, &w_hf, &w_xo, &w_ho,
                    &b_f, &b_o, &c0, &out, &acc};
    hipLaunchCooperativeKernel((const void*)lstm_fused, dim3(NBLK), dim3(256),
                               args, 0, stream);
}

// Round 3
// 30.618 us; speedup vs baseline: 4.4233x; 4.4233x over previous
//
#include <hip/hip_runtime.h>
#include <math.h>

// Geometry (fixed by the reference).
#define HS  2048   // hidden size (output columns)
#define DIN 2048   // input dim (reduction length)
#define CT  16     // columns per tile
#define NT  (HS / CT)  // 128 column tiles

// ---------------------------------------------------------------------------
// Kernel 1: column-split GEMV, full-K reduction in-block. No atomics, no
// init required (zp is fully overwritten every call -> poison-proof).
//   block b: mat = b & 3 (0:w_xf*x 1:w_hf*h0 2:w_xo*x 3:w_ho*h0),
//            tile = b >> 2 (16-column strip)
//   thread t: tx = t & 15 (column within tile), ty = t >> 4 (row phase);
//             accumulates rows r = ty + 16k, k = 0..127.
// Algebra note: cell = f*c0 + dot(i,c) where dot(i,c) is a scalar broadcast;
// the mean/std normalization cancels any constant shift, so the i and c
// gates (w_xi, w_hi, w_xc, w_hc, b_i, b_c) are dead. Only f and o survive.
// ---------------------------------------------------------------------------
__global__ __launch_bounds__(256) void gemv_cols(
        const float* __restrict__ x,    const float* __restrict__ h0,
        const float* __restrict__ w_xf, const float* __restrict__ w_hf,
        const float* __restrict__ w_xo, const float* __restrict__ w_ho,
        float* __restrict__ zp /* [4][HS] */) {
    const int b    = blockIdx.x;
    const int mat  = b & 3;
    const int tile = b >> 2;

    const float* W;
    const float* vec;
    switch (mat) {
        case 0:  W = w_xf; vec = x;  break;
        case 1:  W = w_hf; vec = h0; break;
        case 2:  W = w_xo; vec = x;  break;
        default: W = w_ho; vec = h0; break;
    }

    __shared__ float sv[DIN];       // staged x or h0 (8 KB)
    __shared__ float part[4][CT];   // per-wave column partials

    // stage the vector (coalesced float4)
    {
        const float4* v4 = reinterpret_cast<const float4*>(vec);
        float4* s4 = reinterpret_cast<float4*>(sv);
        for (int i = threadIdx.x; i < DIN / 4; i += 256) s4[i] = v4[i];
    }
    __syncthreads();

    const int tx = threadIdx.x & (CT - 1);
    const int ty = threadIdx.x >> 4;          // 0..15
    const int j  = tile * CT + tx;            // global column
    const float* wp = W + (size_t)ty * HS + j;

    // full-K accumulation: rows ty + 16k; 16 loads in flight per window,
    // 4 rotating accumulators to break the FMA dependence chain.
    float a[4] = {0.f, 0.f, 0.f, 0.f};
#pragma unroll 16
    for (int k = 0; k < 128; ++k) {
        a[k & 3] = fmaf(sv[ty + (k << 4)], wp[(size_t)k << 15], a[k & 3]);
    }
    float s = (a[0] + a[1]) + (a[2] + a[3]);

    // reduce 16 row-phases per column: ty low 2 bits live in-wave (lanes
    // tx, tx+16, tx+32, tx+48), high 2 bits across the 4 waves via LDS.
    s += __shfl_xor(s, 16);
    s += __shfl_xor(s, 32);
    if ((threadIdx.x & 63) < CT) part[threadIdx.x >> 6][tx] = s;
    __syncthreads();
    if (threadIdx.x < CT) {
        const float t = (part[0][tx] + part[1][tx]) + (part[2][tx] + part[3][tx]);
        zp[mat * HS + tile * CT + tx] = t;
    }
}

// ---------------------------------------------------------------------------
// Kernel 2: gates + dot-cancelled normalization + output (single block).
// h = o * tanh( (f*c0 - mean(f*c0)) / (std(f*c0, ddof=1) + 1e-5) )
// ---------------------------------------------------------------------------
__global__ __launch_bounds__(256) void finalize(
        const float* __restrict__ zp,
        const float* __restrict__ b_f, const float* __restrict__ b_o,
        const float* __restrict__ c0,  float* __restrict__ out) {
    const int t    = threadIdx.x;   // 256 threads, 8 elements each
    const int lane = t & 63;
    const int wv   = t >> 6;
    __shared__ float red[2][4];

    float v[8], og[8];
    float lsum = 0.f;
#pragma unroll
    for (int k = 0; k < 2; ++k) {
        const int j = t * 8 + k * 4;
        const float4 zxf = *reinterpret_cast<const float4*>(zp + 0 * HS + j);
        const float4 zhf = *reinterpret_cast<const float4*>(zp + 1 * HS + j);
        const float4 zxo = *reinterpret_cast<const float4*>(zp + 2 * HS + j);
        const float4 zho = *reinterpret_cast<const float4*>(zp + 3 * HS + j);
        const float4 bf  = *reinterpret_cast<const float4*>(b_f + j);
        const float4 bo  = *reinterpret_cast<const float4*>(b_o + j);
        const float4 cv  = *reinterpret_cast<const float4*>(c0 + j);
        const float zfv[4] = {zxf.x + zhf.x + bf.x, zxf.y + zhf.y + bf.y,
                              zxf.z + zhf.z + bf.z, zxf.w + zhf.w + bf.w};
        const float zov[4] = {zxo.x + zho.x + bo.x, zxo.y + zho.y + bo.y,
                              zxo.z + zho.z + bo.z, zxo.w + zho.w + bo.w};
        const float ccv[4] = {cv.x, cv.y, cv.z, cv.w};
#pragma unroll
        for (int q = 0; q < 4; ++q) {
            const float fg = 1.f / (1.f + expf(-zfv[q]));
            const float oo = 1.f / (1.f + expf(-zov[q]));
            const float vv = fg * ccv[q];
            v[k * 4 + q]  = vv;
            og[k * 4 + q] = oo;
            lsum += vv;
        }
    }

    // block-reduce sum(v) -> mean
#pragma unroll
    for (int s = 32; s > 0; s >>= 1) lsum += __shfl_down(lsum, s);
    if (lane == 0) red[0][wv] = lsum;
    __syncthreads();
    const float mean = (red[0][0] + red[0][1] + red[0][2] + red[0][3]) * (1.f / 2048.f);

    // block-reduce sum((v-mean)^2) -> std (ddof=1)
    float lss = 0.f;
#pragma unroll
    for (int e = 0; e < 8; ++e) {
        const float d = v[e] - mean;
        lss += d * d;
    }
#pragma unroll
    for (int s = 32; s > 0; s >>= 1) lss += __shfl_down(lss, s);
    if (lane == 0) red[1][wv] = lss;
    __syncthreads();
    const float var = (red[1][0] + red[1][1] + red[1][2] + red[1][3]) * (1.f / 2047.f);
    const float inv = 1.f / (sqrtf(var) + 1e-5f);

#pragma unroll
    for (int k = 0; k < 2; ++k) {
        const int j = t * 8 + k * 4;
        float4 r;
        r.x = og[k * 4 + 0] * tanhf((v[k * 4 + 0] - mean) * inv);
        r.y = og[k * 4 + 1] * tanhf((v[k * 4 + 1] - mean) * inv);
        r.z = og[k * 4 + 2] * tanhf((v[k * 4 + 2] - mean) * inv);
        r.w = og[k * 4 + 3] * tanhf((v[k * 4 + 3] - mean) * inv);
        *reinterpret_cast<float4*>(out + j) = r;
    }
}

extern "C" void kernel_launch(void* const* d_in, const int* in_sizes, int n_in,
                              void* d_out, int out_size, void* d_ws, size_t ws_size,
                              hipStream_t stream) {
    // setup_inputs order:
    // 0:x 1:w_xi 2:w_xf 3:w_xo 4:w_xc 5:w_hi 6:w_hf 7:w_ho 8:w_hc
    // 9:b_i 10:b_f 11:b_o 12:b_c 13:h0 14:c0
    const float* x    = (const float*)d_in[0];
    const float* w_xf = (const float*)d_in[2];
    const float* w_xo = (const float*)d_in[3];
    const float* w_hf = (const float*)d_in[6];
    const float* w_ho = (const float*)d_in[7];
    const float* b_f  = (const float*)d_in[10];
    const float* b_o  = (const float*)d_in[11];
    const float* h0   = (const float*)d_in[13];
    const float* c0   = (const float*)d_in[14];
    float* out = (float*)d_out;
    float* zp  = (float*)d_ws;  // [4][2048] fp32 partials, fully overwritten

    gemv_cols<<<NT * 4, 256, 0, stream>>>(x, h0, w_xf, w_hf, w_xo, w_ho, zp);
    finalize<<<1, 256, 0, stream>>>(zp, b_f, b_o, c0, out);
}